// Round 4
// baseline (72.835 us; speedup 1.0000x reference)
//
#include <hip/hip_runtime.h>

#define BATCH       65536
#define FEAT        256
#define NUM_CLASSES 10000
#define ALPHA       0.5f
#define PREP_T      1024

// ---------------------------------------------------------------------------
// Phase 1 (single block, one CU): zero + histogram + exclusive scan + scatter,
// all in LDS. Replaces 4 kernels and their global round-trips.
//   outputs: offsets[NUM_CLASSES+1] (exclusive prefix, last = BATCH)
//            sidx[BATCH]            (sample indices, class-sorted)
// ---------------------------------------------------------------------------
__global__ __launch_bounds__(PREP_T) void prep_kernel(
    const int* __restrict__ y_true,
    int*       __restrict__ offsets,
    int*       __restrict__ sidx)
{
    __shared__ int h[NUM_CLASSES];     // 40 KB: hist -> cursor
    __shared__ int wsum[16];
    __shared__ int wbase[16];

    const int t    = threadIdx.x;
    const int lane = t & 63;
    const int wave = t >> 6;

    // zero hist
    for (int i = t; i < NUM_CLASSES; i += PREP_T) h[i] = 0;
    __syncthreads();

    // histogram via LDS atomics; int4 coalesced label reads
    const int4* y4 = reinterpret_cast<const int4*>(y_true);
    for (int i = t; i < BATCH / 4; i += PREP_T) {
        int4 c4 = y4[i];
        atomicAdd(&h[c4.x], 1);
        atomicAdd(&h[c4.y], 1);
        atomicAdd(&h[c4.z], 1);
        atomicAdd(&h[c4.w], 1);
    }
    __syncthreads();

    // exclusive scan of h[0..C) in place (thread-serial-10 + wave shfl scan)
    const int PER    = 10;             // 1024*10 >= 10000
    const int base_i = t * PER;
    int v[PER];
    int sum = 0;
    #pragma unroll
    for (int j = 0; j < PER; ++j) {
        int i = base_i + j;
        int x = (i < NUM_CLASSES) ? h[i] : 0;
        v[j] = sum;                    // exclusive local prefix
        sum += x;
    }
    int inc = sum;
    #pragma unroll
    for (int off = 1; off < 64; off <<= 1) {
        int u = __shfl_up(inc, off, 64);
        if (lane >= off) inc += u;
    }
    if (lane == 63) wsum[wave] = inc;
    __syncthreads();
    if (t < 16) {
        int x = wsum[t];
        int winc = x;
        #pragma unroll
        for (int off = 1; off < 16; off <<= 1) {
            int u = __shfl_up(winc, off, 64);
            if (t >= off) winc += u;
        }
        wbase[t] = winc - x;           // exclusive over wave totals
    }
    __syncthreads();
    const int texcl = wbase[wave] + (inc - sum);
    #pragma unroll
    for (int j = 0; j < PER; ++j) {
        int i = base_i + j;
        if (i < NUM_CLASSES) {
            int o = texcl + v[j];
            h[i]       = o;            // becomes the scatter cursor
            offsets[i] = o;            // pristine copy for class_kernel
        }
    }
    if (t == 0) offsets[NUM_CLASSES] = BATCH;
    __syncthreads();

    // scatter: class-sorted sample indices (y_true re-read is L2-hot)
    for (int i = t; i < BATCH / 4; i += PREP_T) {
        int4 c4 = y4[i];
        int b   = i * 4;
        sidx[atomicAdd(&h[c4.x], 1)] = b + 0;
        sidx[atomicAdd(&h[c4.y], 1)] = b + 1;
        sidx[atomicAdd(&h[c4.z], 1)] = b + 2;
        sidx[atomicAdd(&h[c4.w], 1)] = b + 3;
    }
}

// ---------------------------------------------------------------------------
// Phase 2: one wave per class. Gather the class's y_pred rows (1KB coalesced
// per row), accumulate sum_y in registers, emit per-sample loss, then write
// new_centers = c - ALPHA*(n*c - sum_y)/(n+1) directly.
// ---------------------------------------------------------------------------
__global__ __launch_bounds__(256) void class_kernel(
    const float* __restrict__ y_pred,
    const float* __restrict__ centers,
    const int*   __restrict__ offsets,
    const int*   __restrict__ sidx,
    float*       __restrict__ loss,
    float*       __restrict__ new_centers)
{
    const int wave = threadIdx.x >> 6;
    const int lane = threadIdx.x & 63;
    const int c    = blockIdx.x * 4 + wave;      // exact: 2500*4 = 10000
    if (c >= NUM_CLASSES) return;

    const int base = offsets[c];
    const int n    = offsets[c + 1] - base;

    float4 cv = reinterpret_cast<const float4*>(centers + (size_t)c * FEAT)[lane];
    float4 s  = make_float4(0.f, 0.f, 0.f, 0.f);

    for (int k0 = 0; k0 < n; k0 += 64) {
        const int nb = min(64, n - k0);
        int myidx = (lane < nb) ? sidx[base + k0 + lane] : 0;
        for (int k = 0; k < nb; ++k) {
            const int idx = __shfl(myidx, k, 64);
            float4 y = reinterpret_cast<const float4*>(y_pred + (size_t)idx * FEAT)[lane];
            s.x += y.x; s.y += y.y; s.z += y.z; s.w += y.w;

            float dx = cv.x - y.x, dy = cv.y - y.y,
                  dz = cv.z - y.z, dw = cv.w - y.w;
            float l = dx*dx + dy*dy + dz*dz + dw*dw;
            #pragma unroll
            for (int off = 32; off > 0; off >>= 1)
                l += __shfl_down(l, off, 64);
            if (lane == 0) loss[idx] = l;
        }
    }

    const float fn    = (float)n;
    const float scale = ALPHA / (fn + 1.0f);
    float4 o;
    o.x = cv.x - (fn * cv.x - s.x) * scale;
    o.y = cv.y - (fn * cv.y - s.y) * scale;
    o.z = cv.z - (fn * cv.z - s.z) * scale;
    o.w = cv.w - (fn * cv.w - s.w) * scale;
    reinterpret_cast<float4*>(new_centers + (size_t)c * FEAT)[lane] = o;
}

extern "C" void kernel_launch(void* const* d_in, const int* in_sizes, int n_in,
                              void* d_out, int out_size, void* d_ws, size_t ws_size,
                              hipStream_t stream)
{
    const float* y_pred  = (const float*)d_in[0];
    const float* centers = (const float*)d_in[1];
    const int*   y_true  = (const int*)d_in[2];

    float* out         = (float*)d_out;
    float* loss        = out;                 // [BATCH]
    float* new_centers = out + BATCH;         // [NUM_CLASSES * FEAT]

    int* offsets = (int*)d_ws;                // [NUM_CLASSES + 1]
    int* sidx    = offsets + NUM_CLASSES + 1; // [BATCH]

    prep_kernel <<<1, PREP_T, 0, stream>>>(y_true, offsets, sidx);
    class_kernel<<<NUM_CLASSES / 4, 256, 0, stream>>>(
        y_pred, centers, offsets, sidx, loss, new_centers);
}

// Round 5
// 66.168 us; speedup vs baseline: 1.1007x; 1.1007x over previous
//
#include <hip/hip_runtime.h>

#define BATCH       65536
#define FEAT        256
#define NUM_CLASSES 10000
#define ALPHA       0.5f

#define HB   16      // histogram slice blocks
#define HT   1024    // threads in hist/scan blocks
#define SEG  10      // ceil(NUM_CLASSES / HT)

// ---------------------------------------------------------------------------
// K1: per-slice LDS histogram. Block b counts samples [b*4096, (b+1)*4096)
// into LDS (zeroed in-kernel -> no global zero pass), writes partial[b][c]
// coalesced. 4K LDS atomics per CU, 16 CUs in parallel.
// ---------------------------------------------------------------------------
__global__ __launch_bounds__(HT) void hist_kernel(const int* __restrict__ y_true,
                                                  int* __restrict__ partial)
{
    __shared__ int h[NUM_CLASSES];
    const int t = threadIdx.x;
    const int b = blockIdx.x;

    for (int i = t; i < NUM_CLASSES; i += HT) h[i] = 0;
    __syncthreads();

    const int4 c4 = reinterpret_cast<const int4*>(y_true)[b * HT + t];
    atomicAdd(&h[c4.x], 1);
    atomicAdd(&h[c4.y], 1);
    atomicAdd(&h[c4.z], 1);
    atomicAdd(&h[c4.w], 1);
    __syncthreads();

    int* out = partial + b * NUM_CLASSES;
    for (int i = t; i < NUM_CLASSES; i += HT) out[i] = h[i];
}

// ---------------------------------------------------------------------------
// K2: combine + scan + scatter. Each of the 16 blocks redundantly:
//   - sums partial[0..15][c] (coalesced: lane->consecutive c) into colsum,
//     and its own-prefix sum over b' < blockIdx (mp),
//   - block-scans the 10000 colsums (10 segments, wave shfl + 16-wave LDS),
//   - cursor[c] = offsets[c] + mp  (per-block scatter base, in LDS),
//   - scatters its 4096 sample indices via LDS atomic cursors.
// Block 0 additionally publishes offsets[] for the class kernel.
// ---------------------------------------------------------------------------
__global__ __launch_bounds__(HT) void scanscat_kernel(const int* __restrict__ y_true,
                                                      const int* __restrict__ partial,
                                                      int* __restrict__ offsets,
                                                      int* __restrict__ sidx)
{
    __shared__ int cursor[NUM_CLASSES];       // 40 KB
    __shared__ int wsum[16], wbase[16];
    __shared__ int carry_s;

    const int t    = threadIdx.x;
    const int lane = t & 63;
    const int wave = t >> 6;
    const int myb  = blockIdx.x;

    // combine partials: per segment j, this thread owns class c = j*1024 + t
    int cs[SEG], mp[SEG];
    #pragma unroll
    for (int j = 0; j < SEG; ++j) {
        const int c = j * HT + t;
        int s_ = 0, m_ = 0;
        if (c < NUM_CLASSES) {
            #pragma unroll
            for (int b = 0; b < HB; ++b) {
                const int v = partial[b * NUM_CLASSES + c];
                s_ += v;
                if (b < myb) m_ += v;
            }
        }
        cs[j] = s_;
        mp[j] = m_;
    }

    if (t == 0) carry_s = 0;
    __syncthreads();

    // segmented block scan over class order
    for (int j = 0; j < SEG; ++j) {
        const int x = cs[j];
        int inc = x;
        #pragma unroll
        for (int off = 1; off < 64; off <<= 1) {
            const int u = __shfl_up(inc, off, 64);
            if (lane >= off) inc += u;
        }
        if (lane == 63) wsum[wave] = inc;
        __syncthreads();
        if (t < 16) {
            const int xx = wsum[t];
            int winc = xx;
            #pragma unroll
            for (int off = 1; off < 16; off <<= 1) {
                const int u = __shfl_up(winc, off, 64);
                if (t >= off) winc += u;
            }
            wbase[t] = winc - xx;             // exclusive over wave totals
        }
        __syncthreads();
        const int exc = carry_s + wbase[wave] + (inc - x);
        const int c   = j * HT + t;
        if (c < NUM_CLASSES) {
            cursor[c] = exc + mp[j];
            if (myb == 0) offsets[c] = exc;
        }
        __syncthreads();
        if (t == HT - 1) carry_s += wbase[15] + wsum[15];   // segment total
        __syncthreads();
    }
    if (myb == 0 && t == 0) offsets[NUM_CLASSES] = BATCH;
    // (final loop barrier guarantees cursor[] complete for all threads)

    // scatter this block's 4096 samples (y_true slice is L2/L3-hot)
    const int4 c4 = reinterpret_cast<const int4*>(y_true)[myb * HT + t];
    const int s0  = (myb * HT + t) * 4;
    sidx[atomicAdd(&cursor[c4.x], 1)] = s0 + 0;
    sidx[atomicAdd(&cursor[c4.y], 1)] = s0 + 1;
    sidx[atomicAdd(&cursor[c4.z], 1)] = s0 + 2;
    sidx[atomicAdd(&cursor[c4.w], 1)] = s0 + 3;
}

// ---------------------------------------------------------------------------
// K3: one wave per class. Gather the class's y_pred rows (1KB coalesced per
// row), accumulate sum_y in registers, emit per-sample loss, write
// new_centers = c - ALPHA*(n*c - sum_y)/(n+1).
// ---------------------------------------------------------------------------
__global__ __launch_bounds__(256) void class_kernel(
    const float* __restrict__ y_pred,
    const float* __restrict__ centers,
    const int*   __restrict__ offsets,
    const int*   __restrict__ sidx,
    float*       __restrict__ loss,
    float*       __restrict__ new_centers)
{
    const int wave = threadIdx.x >> 6;
    const int lane = threadIdx.x & 63;
    const int c    = blockIdx.x * 4 + wave;      // exact: 2500*4 = 10000
    if (c >= NUM_CLASSES) return;

    const int base = offsets[c];
    const int n    = offsets[c + 1] - base;

    float4 cv = reinterpret_cast<const float4*>(centers + (size_t)c * FEAT)[lane];
    float4 s  = make_float4(0.f, 0.f, 0.f, 0.f);

    for (int k0 = 0; k0 < n; k0 += 64) {
        const int nb = min(64, n - k0);
        int myidx = (lane < nb) ? sidx[base + k0 + lane] : 0;
        for (int k = 0; k < nb; ++k) {
            const int idx = __shfl(myidx, k, 64);
            float4 y = reinterpret_cast<const float4*>(y_pred + (size_t)idx * FEAT)[lane];
            s.x += y.x; s.y += y.y; s.z += y.z; s.w += y.w;

            float dx = cv.x - y.x, dy = cv.y - y.y,
                  dz = cv.z - y.z, dw = cv.w - y.w;
            float l = dx*dx + dy*dy + dz*dz + dw*dw;
            #pragma unroll
            for (int off = 32; off > 0; off >>= 1)
                l += __shfl_down(l, off, 64);
            if (lane == 0) loss[idx] = l;
        }
    }

    const float fn    = (float)n;
    const float scale = ALPHA / (fn + 1.0f);
    float4 o;
    o.x = cv.x - (fn * cv.x - s.x) * scale;
    o.y = cv.y - (fn * cv.y - s.y) * scale;
    o.z = cv.z - (fn * cv.z - s.z) * scale;
    o.w = cv.w - (fn * cv.w - s.w) * scale;
    reinterpret_cast<float4*>(new_centers + (size_t)c * FEAT)[lane] = o;
}

extern "C" void kernel_launch(void* const* d_in, const int* in_sizes, int n_in,
                              void* d_out, int out_size, void* d_ws, size_t ws_size,
                              hipStream_t stream)
{
    const float* y_pred  = (const float*)d_in[0];
    const float* centers = (const float*)d_in[1];
    const int*   y_true  = (const int*)d_in[2];

    float* out         = (float*)d_out;
    float* loss        = out;                 // [BATCH]
    float* new_centers = out + BATCH;         // [NUM_CLASSES * FEAT]

    int* partial = (int*)d_ws;                     // [HB * NUM_CLASSES]
    int* offsets = partial + HB * NUM_CLASSES;     // [NUM_CLASSES + 1]
    int* sidx    = offsets + NUM_CLASSES + 1;      // [BATCH]

    hist_kernel    <<<HB, HT, 0, stream>>>(y_true, partial);
    scanscat_kernel<<<HB, HT, 0, stream>>>(y_true, partial, offsets, sidx);
    class_kernel   <<<NUM_CLASSES / 4, 256, 0, stream>>>(
        y_pred, centers, offsets, sidx, loss, new_centers);
}

// Round 6
// 36.713 us; speedup vs baseline: 1.9839x; 1.8023x over previous
//
#include <hip/hip_runtime.h>

#define BATCH       65536
#define FEAT        256
#define NUM_CLASSES 10000
#define ALPHA       0.5f
#define CAP         32     // bucket capacity; Poisson(6.55) max over 10k classes ~21

// ---------------------------------------------------------------------------
// K1: zero per-class counters + overflow counter (40 KB; launch-latency bound)
// ---------------------------------------------------------------------------
__global__ __launch_bounds__(256) void zero_kernel(int* __restrict__ count)
{
    int i = blockIdx.x * 256 + threadIdx.x;
    if (i < NUM_CLASSES + 1) count[i] = 0;
}

// ---------------------------------------------------------------------------
// K2: bucket scatter. pos = atomicAdd(count[c]); bucket[c*CAP+pos] = sample.
// No histogram, no scan. Overflow (pos >= CAP) goes to a (class,idx) list —
// statistically never taken for this data, but correct if it is.
// ---------------------------------------------------------------------------
__global__ __launch_bounds__(256) void bucket_kernel(const int* __restrict__ y_true,
                                                     int* __restrict__ count,
                                                     int* __restrict__ bucket,
                                                     int* __restrict__ ovf)
{
    const int i  = blockIdx.x * 256 + threadIdx.x;     // 0 .. BATCH/4-1
    const int4 c4 = reinterpret_cast<const int4*>(y_true)[i];
    const int s0  = i * 4;
    int* ovfcnt = count + NUM_CLASSES;

    const int cs[4] = {c4.x, c4.y, c4.z, c4.w};
    #pragma unroll
    for (int j = 0; j < 4; ++j) {
        const int c   = cs[j];
        const int pos = atomicAdd(&count[c], 1);
        if (pos < CAP) {
            bucket[c * CAP + pos] = s0 + j;
        } else {
            const int o = atomicAdd(ovfcnt, 1);
            ovf[2 * o]     = c;
            ovf[2 * o + 1] = s0 + j;
        }
    }
}

// ---------------------------------------------------------------------------
// K3: one wave per class. Bucket row (<=32 ints) is ONE 128B load per wave.
// Gather the class's y_pred rows (1KB coalesced per row), accumulate sum_y,
// emit per-sample loss, write new_centers = c - ALPHA*(n*c - sum_y)/(n+1).
// ---------------------------------------------------------------------------
__global__ __launch_bounds__(256) void class_kernel(
    const float* __restrict__ y_pred,
    const float* __restrict__ centers,
    const int*   __restrict__ count,
    const int*   __restrict__ bucket,
    const int*   __restrict__ ovf,
    float*       __restrict__ loss,
    float*       __restrict__ new_centers)
{
    const int wave = threadIdx.x >> 6;
    const int lane = threadIdx.x & 63;
    const int c    = blockIdx.x * 4 + wave;      // exact: 2500*4 = 10000
    if (c >= NUM_CLASSES) return;

    const int n_total = count[c];
    const int n       = min(n_total, CAP);

    float4 cv = reinterpret_cast<const float4*>(centers + (size_t)c * FEAT)[lane];
    float4 s  = make_float4(0.f, 0.f, 0.f, 0.f);

    const int bidx = (lane < n) ? bucket[c * CAP + lane] : 0;

    for (int k = 0; k < n; ++k) {
        const int idx = __shfl(bidx, k, 64);
        float4 y = reinterpret_cast<const float4*>(y_pred + (size_t)idx * FEAT)[lane];
        s.x += y.x; s.y += y.y; s.z += y.z; s.w += y.w;

        float dx = cv.x - y.x, dy = cv.y - y.y,
              dz = cv.z - y.z, dw = cv.w - y.w;
        float l = dx*dx + dy*dy + dz*dz + dw*dw;
        #pragma unroll
        for (int off = 32; off > 0; off >>= 1)
            l += __shfl_down(l, off, 64);
        if (lane == 0) loss[idx] = l;
    }

    // overflow fallback (never taken for this data, kept for correctness)
    if (n_total > CAP) {
        const int m = count[NUM_CLASSES];
        for (int o = 0; o < m; ++o) {
            if (ovf[2 * o] == c) {
                const int idx = ovf[2 * o + 1];
                float4 y = reinterpret_cast<const float4*>(y_pred + (size_t)idx * FEAT)[lane];
                s.x += y.x; s.y += y.y; s.z += y.z; s.w += y.w;
                float dx = cv.x - y.x, dy = cv.y - y.y,
                      dz = cv.z - y.z, dw = cv.w - y.w;
                float l = dx*dx + dy*dy + dz*dz + dw*dw;
                #pragma unroll
                for (int off = 32; off > 0; off >>= 1)
                    l += __shfl_down(l, off, 64);
                if (lane == 0) loss[idx] = l;
            }
        }
    }

    const float fn    = (float)n_total;
    const float scale = ALPHA / (fn + 1.0f);
    float4 o;
    o.x = cv.x - (fn * cv.x - s.x) * scale;
    o.y = cv.y - (fn * cv.y - s.y) * scale;
    o.z = cv.z - (fn * cv.z - s.z) * scale;
    o.w = cv.w - (fn * cv.w - s.w) * scale;
    reinterpret_cast<float4*>(new_centers + (size_t)c * FEAT)[lane] = o;
}

extern "C" void kernel_launch(void* const* d_in, const int* in_sizes, int n_in,
                              void* d_out, int out_size, void* d_ws, size_t ws_size,
                              hipStream_t stream)
{
    const float* y_pred  = (const float*)d_in[0];
    const float* centers = (const float*)d_in[1];
    const int*   y_true  = (const int*)d_in[2];

    float* out         = (float*)d_out;
    float* loss        = out;                 // [BATCH]
    float* new_centers = out + BATCH;         // [NUM_CLASSES * FEAT]

    int* count  = (int*)d_ws;                         // [NUM_CLASSES + 1]
    int* bucket = count + NUM_CLASSES + 1;            // [NUM_CLASSES * CAP]
    int* ovf    = bucket + NUM_CLASSES * CAP;         // [2 * BATCH]

    zero_kernel  <<<(NUM_CLASSES + 256) / 256, 256, 0, stream>>>(count);
    bucket_kernel<<<BATCH / 4 / 256, 256, 0, stream>>>(y_true, count, bucket, ovf);
    class_kernel <<<NUM_CLASSES / 4, 256, 0, stream>>>(
        y_pred, centers, count, bucket, ovf, loss, new_centers);
}